// Round 2
// baseline (804.500 us; speedup 1.0000x reference)
//
#include <hip/hip_runtime.h>

constexpr int FD = 128;          // feature dim
constexpr int NNODES = 50000;
constexpr int NPAIRS = 800000;

typedef _Float16 half8 __attribute__((ext_vector_type(8)));
typedef __fp16 fp16x2 __attribute__((ext_vector_type(2)));
typedef float f32x4 __attribute__((ext_vector_type(4)));

#define MFMA16(a, b, c) __builtin_amdgcn_mfma_f32_16x16x32_f16((a), (b), (c), 0, 0, 0)

// f32 -> fp16 hi (RTZ) + fp16 lo (residual). hi+lo reproduces f32 to ~2^-21 rel.
__device__ __forceinline__ void cvt_hilo2(float a, float b, unsigned& hi, unsigned& lo) {
    fp16x2 h = __builtin_amdgcn_cvt_pkrtz(a, b);
    float ra = a - (float)h[0];
    float rb = b - (float)h[1];
    fp16x2 l = __builtin_amdgcn_cvt_pkrtz(ra, rb);
    hi = __builtin_bit_cast(unsigned, h);
    lo = __builtin_bit_cast(unsigned, l);
}

__device__ __forceinline__ void cvt_hilo8(const float* s, half8& hi, half8& lo) {
    union { half8 v; unsigned u[4]; } uh, ul;
    cvt_hilo2(s[0], s[1], uh.u[0], ul.u[0]);
    cvt_hilo2(s[2], s[3], uh.u[1], ul.u[1]);
    cvt_hilo2(s[4], s[5], uh.u[2], ul.u[2]);
    cvt_hilo2(s[6], s[7], uh.u[3], ul.u[3]);
    hi = uh.v; lo = ul.v;
}

// XOR swizzle (byte ^= (row&7)<<4, expressed in f16 elements) for [64][128] f16 tile.
__device__ __forceinline__ int swz(int row, int col) {
    return row * FD + (col ^ ((row & 7) << 3));
}

// Register-resident W1^T fragments: wave owns n-tiles {2*wave, 2*wave+1}.
// A'[n][k] = W1[arow0 + k][n]; element j of (ks) fragment covers k = ks*32 + g*8 + j.
__device__ __forceinline__ void load_w1_frags(const float* __restrict__ W1, int arow0,
                                              int r, int g, int wave,
                                              half8 Ahi[2][4], half8 Alo[2][4]) {
#pragma unroll
    for (int nt = 0; nt < 2; ++nt) {
        int n = (wave * 2 + nt) * 16 + r;
#pragma unroll
        for (int ks = 0; ks < 4; ++ks) {
            float s[8];
#pragma unroll
            for (int j = 0; j < 8; ++j)
                s[j] = W1[(arow0 + ks * 32 + g * 8 + j) * FD + n];
            cvt_hilo8(s, Ahi[nt][ks], Alo[nt][ks]);
        }
    }
}

// ---------------- precompute: xab[node][0:128]=x@W1a, [128:256]=x@W1b ----------------
__global__ __launch_bounds__(256, 2) void node_kernel(
    const float* __restrict__ x, const float* __restrict__ W1,
    float* __restrict__ xab)
{
    __shared__ __align__(16) _Float16 sHi[64 * FD];
    __shared__ __align__(16) _Float16 sLo[64 * FD];

    const int tid = threadIdx.x;
    const int lane = tid & 63, wave = tid >> 6;
    const int r = lane & 15, g = lane >> 4;
    const int h = blockIdx.y;            // 0 -> W1a, 1 -> W1b

    half8 Ahi[2][4], Alo[2][4];
    load_w1_frags(W1, h * FD, r, g, wave, Ahi, Alo);

    const int m0 = blockIdx.x * 64;
    const f32x4* xv = reinterpret_cast<const f32x4*>(x);
#pragma unroll
    for (int rr = 0; rr < 8; ++rr) {
        int v = tid + 256 * rr;
        int row = v >> 5, c4 = v & 31;
        int srow = m0 + row; if (srow >= NNODES) srow = NNODES - 1;
        f32x4 d = xv[(size_t)srow * 32 + c4];
        unsigned h0, l0, h1, l1;
        cvt_hilo2(d[0], d[1], h0, l0);
        cvt_hilo2(d[2], d[3], h1, l1);
        int sidx = swz(row, c4 * 4);
        *reinterpret_cast<uint2*>(&sHi[sidx]) = make_uint2(h0, h1);
        *reinterpret_cast<uint2*>(&sLo[sidx]) = make_uint2(l0, l1);
    }
    __syncthreads();

    f32x4 acc[2][4] = {};
#pragma unroll
    for (int ks = 0; ks < 4; ++ks) {
#pragma unroll
        for (int mt = 0; mt < 4; ++mt) {
            int ridx = swz(mt * 16 + r, ks * 32 + g * 8);
            half8 bh = *reinterpret_cast<const half8*>(&sHi[ridx]);
            half8 bl = *reinterpret_cast<const half8*>(&sLo[ridx]);
#pragma unroll
            for (int nt = 0; nt < 2; ++nt) {
                acc[nt][mt] = MFMA16(Ahi[nt][ks], bh, acc[nt][mt]);
                acc[nt][mt] = MFMA16(Alo[nt][ks], bh, acc[nt][mt]);
                acc[nt][mt] = MFMA16(Ahi[nt][ks], bl, acc[nt][mt]);
            }
        }
    }

#pragma unroll
    for (int mt = 0; mt < 4; ++mt) {
        int node = m0 + mt * 16 + r;
        if (node < NNODES) {
#pragma unroll
            for (int nt = 0; nt < 2; ++nt) {
                int nc = h * FD + (wave * 2 + nt) * 16 + g * 4;
                *reinterpret_cast<f32x4*>(&xab[(size_t)node * 256 + nc]) = acc[nt][mt];
            }
        }
    }
}

// ---------------- fused pair kernel ----------------
// C'[n][m] = W1c^T . w_ij^T  (n = hidden feature, m = pair). Epilogue: gather
// xab rows, +b1, silu, dot W2, cross-lane + cross-wave reduce, store out[m].
__global__ __launch_bounds__(256, 2) void pair_kernel(
    const float* __restrict__ wij, const float* __restrict__ W1,
    const float* __restrict__ b1, const float* __restrict__ W2,
    const float* __restrict__ b2, const int* __restrict__ idx_i,
    const int* __restrict__ idx_j, const float* __restrict__ xab,
    float* __restrict__ out)
{
    __shared__ __align__(16) _Float16 sHi[64 * FD];
    __shared__ __align__(16) _Float16 sLo[64 * FD];
    __shared__ float sred[4][64];

    const int tid = threadIdx.x;
    const int lane = tid & 63, wave = tid >> 6;
    const int r = lane & 15, g = lane >> 4;

    half8 Ahi[2][4], Alo[2][4];
    load_w1_frags(W1, 2 * FD, r, g, wave, Ahi, Alo);   // W1c rows 256..383

    f32x4 b1v[2], w2v[2];
#pragma unroll
    for (int nt = 0; nt < 2; ++nt) {
        int nc = (wave * 2 + nt) * 16 + g * 4;
        b1v[nt] = *reinterpret_cast<const f32x4*>(&b1[nc]);
        w2v[nt] = *reinterpret_cast<const f32x4*>(&W2[nc]);
    }
    const float b2v = b2[0];

    for (int t = blockIdx.x; t < NPAIRS / 64; t += gridDim.x) {
        const int m0 = t * 64;
        const f32x4* wrow = reinterpret_cast<const f32x4*>(wij + (size_t)m0 * FD);
#pragma unroll
        for (int rr = 0; rr < 8; ++rr) {
            int v = tid + 256 * rr;
            int row = v >> 5, c4 = v & 31;
            f32x4 d = wrow[v];
            unsigned h0, l0, h1, l1;
            cvt_hilo2(d[0], d[1], h0, l0);
            cvt_hilo2(d[2], d[3], h1, l1);
            int sidx = swz(row, c4 * 4);
            *reinterpret_cast<uint2*>(&sHi[sidx]) = make_uint2(h0, h1);
            *reinterpret_cast<uint2*>(&sLo[sidx]) = make_uint2(l0, l1);
        }
        __syncthreads();

        f32x4 acc[2][4] = {};
#pragma unroll
        for (int ks = 0; ks < 4; ++ks) {
#pragma unroll
            for (int mt = 0; mt < 4; ++mt) {
                int ridx = swz(mt * 16 + r, ks * 32 + g * 8);
                half8 bh = *reinterpret_cast<const half8*>(&sHi[ridx]);
                half8 bl = *reinterpret_cast<const half8*>(&sLo[ridx]);
#pragma unroll
                for (int nt = 0; nt < 2; ++nt) {
                    acc[nt][mt] = MFMA16(Ahi[nt][ks], bh, acc[nt][mt]);
                    acc[nt][mt] = MFMA16(Alo[nt][ks], bh, acc[nt][mt]);
                    acc[nt][mt] = MFMA16(Ahi[nt][ks], bl, acc[nt][mt]);
                }
            }
        }

        // epilogue: D-frag lane holds m = mt*16 + r (col), n = ntile*16 + g*4 + e (row)
#pragma unroll
        for (int mt = 0; mt < 4; ++mt) {
            int p = m0 + mt * 16 + r;
            int ni = idx_i[p], nj = idx_j[p];
            float ps = 0.f;
#pragma unroll
            for (int nt = 0; nt < 2; ++nt) {
                int nc = (wave * 2 + nt) * 16 + g * 4;
                f32x4 xa = *reinterpret_cast<const f32x4*>(&xab[(size_t)ni * 256 + nc]);
                f32x4 xb = *reinterpret_cast<const f32x4*>(&xab[(size_t)nj * 256 + 128 + nc]);
                f32x4 tv = acc[nt][mt] + b1v[nt] + xa + xb;
#pragma unroll
                for (int e = 0; e < 4; ++e) {
                    float te = tv[e];
                    float hh = te / (1.f + __expf(-te));   // silu
                    ps += hh * w2v[nt][e];
                }
            }
            ps += __shfl_xor(ps, 16);
            ps += __shfl_xor(ps, 32);
            if (g == 0) sred[wave][mt * 16 + r] = ps;
        }
        __syncthreads();
        if (wave == 0)
            out[m0 + lane] = b2v + sred[0][lane] + sred[1][lane] + sred[2][lane] + sred[3][lane];
    }
}

extern "C" void kernel_launch(void* const* d_in, const int* in_sizes, int n_in,
                              void* d_out, int out_size, void* d_ws, size_t ws_size,
                              hipStream_t stream) {
    const float* x   = (const float*)d_in[0];
    const float* wij = (const float*)d_in[1];
    const float* W1  = (const float*)d_in[2];
    const float* b1  = (const float*)d_in[3];
    const float* W2  = (const float*)d_in[4];
    const float* b2  = (const float*)d_in[5];
    const int* ii    = (const int*)d_in[6];
    const int* jj    = (const int*)d_in[7];
    float* out = (float*)d_out;
    float* xab = (float*)d_ws;   // 50000*256*4 = 51.2 MB scratch

    dim3 gnode((NNODES + 63) / 64, 2);
    node_kernel<<<gnode, 256, 0, stream>>>(x, W1, xab);
    pair_kernel<<<1024, 256, 0, stream>>>(wij, W1, b1, W2, b2, ii, jj, xab, out);
}

// Round 3
// 757.844 us; speedup vs baseline: 1.0616x; 1.0616x over previous
//
#include <hip/hip_runtime.h>

constexpr int FD = 128;          // feature dim
constexpr int NNODES = 50000;
constexpr int NPAIRS = 800000;

typedef _Float16 half8 __attribute__((ext_vector_type(8)));
typedef __fp16 fp16x2 __attribute__((ext_vector_type(2)));
typedef float f32x4 __attribute__((ext_vector_type(4)));

#define MFMA16(a, b, c) __builtin_amdgcn_mfma_f32_16x16x32_f16((a), (b), (c), 0, 0, 0)

// f32 -> fp16 hi (RTZ) + fp16 lo (residual). hi+lo reproduces f32 to ~2^-21 rel.
__device__ __forceinline__ void cvt_hilo2(float a, float b, unsigned& hi, unsigned& lo) {
    fp16x2 h = __builtin_amdgcn_cvt_pkrtz(a, b);
    float ra = a - (float)h[0];
    float rb = b - (float)h[1];
    fp16x2 l = __builtin_amdgcn_cvt_pkrtz(ra, rb);
    hi = __builtin_bit_cast(unsigned, h);
    lo = __builtin_bit_cast(unsigned, l);
}

__device__ __forceinline__ void cvt_hilo8(const float* s, half8& hi, half8& lo) {
    union { half8 v; unsigned u[4]; } uh, ul;
    cvt_hilo2(s[0], s[1], uh.u[0], ul.u[0]);
    cvt_hilo2(s[2], s[3], uh.u[1], ul.u[1]);
    cvt_hilo2(s[4], s[5], uh.u[2], ul.u[2]);
    cvt_hilo2(s[6], s[7], uh.u[3], ul.u[3]);
    hi = uh.v; lo = ul.v;
}

// XOR swizzle (byte ^= (row&7)<<4, expressed in f16 elements) for [64][128] f16 tile.
__device__ __forceinline__ int swz(int row, int col) {
    return row * FD + (col ^ ((row & 7) << 3));
}

// Register-resident W1^T fragments: wave owns n-tiles {2*wave, 2*wave+1}.
// A'[n][k] = W1[arow0 + k][n]; element j of (ks) fragment covers k = ks*32 + g*8 + j.
__device__ __forceinline__ void load_w1_frags(const float* __restrict__ W1, int arow0,
                                              int r, int g, int wave,
                                              half8 Ahi[2][4], half8 Alo[2][4]) {
#pragma unroll
    for (int nt = 0; nt < 2; ++nt) {
        int n = (wave * 2 + nt) * 16 + r;
#pragma unroll
        for (int ks = 0; ks < 4; ++ks) {
            float s[8];
#pragma unroll
            for (int j = 0; j < 8; ++j)
                s[j] = W1[(arow0 + ks * 32 + g * 8 + j) * FD + n];
            cvt_hilo8(s, Ahi[nt][ks], Alo[nt][ks]);
        }
    }
}

// ---------------- precompute: xab[node][0:128]=x@W1a, [128:256]=x@W1b ----------------
__global__ __launch_bounds__(256, 2) void node_kernel(
    const float* __restrict__ x, const float* __restrict__ W1,
    float* __restrict__ xab)
{
    __shared__ __align__(16) _Float16 sHi[64 * FD];
    __shared__ __align__(16) _Float16 sLo[64 * FD];

    const int tid = threadIdx.x;
    const int lane = tid & 63, wave = tid >> 6;
    const int r = lane & 15, g = lane >> 4;
    const int h = blockIdx.y;            // 0 -> W1a, 1 -> W1b

    half8 Ahi[2][4], Alo[2][4];
    load_w1_frags(W1, h * FD, r, g, wave, Ahi, Alo);

    const int m0 = blockIdx.x * 64;
    const f32x4* xv = reinterpret_cast<const f32x4*>(x);
#pragma unroll
    for (int rr = 0; rr < 8; ++rr) {
        int v = tid + 256 * rr;
        int row = v >> 5, c4 = v & 31;
        int srow = m0 + row; if (srow >= NNODES) srow = NNODES - 1;
        f32x4 d = xv[(size_t)srow * 32 + c4];
        unsigned h0, l0, h1, l1;
        cvt_hilo2(d[0], d[1], h0, l0);
        cvt_hilo2(d[2], d[3], h1, l1);
        int sidx = swz(row, c4 * 4);
        *reinterpret_cast<uint2*>(&sHi[sidx]) = make_uint2(h0, h1);
        *reinterpret_cast<uint2*>(&sLo[sidx]) = make_uint2(l0, l1);
    }
    __syncthreads();

    f32x4 acc[2][4] = {};
#pragma unroll
    for (int ks = 0; ks < 4; ++ks) {
#pragma unroll
        for (int mt = 0; mt < 4; ++mt) {
            int ridx = swz(mt * 16 + r, ks * 32 + g * 8);
            half8 bh = *reinterpret_cast<const half8*>(&sHi[ridx]);
            half8 bl = *reinterpret_cast<const half8*>(&sLo[ridx]);
#pragma unroll
            for (int nt = 0; nt < 2; ++nt) {
                acc[nt][mt] = MFMA16(Ahi[nt][ks], bh, acc[nt][mt]);
                acc[nt][mt] = MFMA16(Alo[nt][ks], bh, acc[nt][mt]);
                acc[nt][mt] = MFMA16(Ahi[nt][ks], bl, acc[nt][mt]);
            }
        }
    }

#pragma unroll
    for (int mt = 0; mt < 4; ++mt) {
        int node = m0 + mt * 16 + r;
        if (node < NNODES) {
#pragma unroll
            for (int nt = 0; nt < 2; ++nt) {
                int nc = h * FD + (wave * 2 + nt) * 16 + g * 4;
                *reinterpret_cast<f32x4*>(&xab[(size_t)node * 256 + nc]) = acc[nt][mt];
            }
        }
    }
}

// ---------------- fused pair kernel ----------------
// C'[n][m] = W1c^T . w_ij^T  (n = hidden feature, m = pair). Epilogue: gather
// xab rows, +b1, silu, dot W2, cross-lane + cross-wave reduce, store out[m].
// T14 pipeline: next tile's wij + idx prefetched into registers during compute.
__global__ __launch_bounds__(256, 3) void pair_kernel(
    const float* __restrict__ wij, const float* __restrict__ W1,
    const float* __restrict__ b1, const float* __restrict__ W2,
    const float* __restrict__ b2, const int* __restrict__ idx_i,
    const int* __restrict__ idx_j, const float* __restrict__ xab,
    float* __restrict__ out)
{
    __shared__ __align__(16) _Float16 sHi[64 * FD];
    __shared__ __align__(16) _Float16 sLo[64 * FD];
    __shared__ float sred[4][64];

    const int tid = threadIdx.x;
    const int lane = tid & 63, wave = tid >> 6;
    const int r = lane & 15, g = lane >> 4;

    half8 Ahi[2][4], Alo[2][4];
    load_w1_frags(W1, 2 * FD, r, g, wave, Ahi, Alo);   // W1c rows 256..383

    f32x4 b1v[2], w2v[2];
#pragma unroll
    for (int nt = 0; nt < 2; ++nt) {
        int nc = (wave * 2 + nt) * 16 + g * 4;
        b1v[nt] = *reinterpret_cast<const f32x4*>(&b1[nc]);
        w2v[nt] = *reinterpret_cast<const f32x4*>(&W2[nc]);
    }
    const float b2v = b2[0];

    const int ntiles = NPAIRS / 64;
    const f32x4* wv = reinterpret_cast<const f32x4*>(wij);

    int t = blockIdx.x;
    f32x4 P[8];
    int pi[4], pj[4];
    {
        const size_t base = (size_t)t * 2048 + tid;
#pragma unroll
        for (int rr = 0; rr < 8; ++rr) P[rr] = wv[base + 256 * rr];
#pragma unroll
        for (int mt = 0; mt < 4; ++mt) {
            int p = t * 64 + mt * 16 + r;
            pi[mt] = idx_i[p]; pj[mt] = idx_j[p];
        }
    }

    for (; t < ntiles; t += gridDim.x) {
        // ---- stage current tile from registers into LDS (cvt f32 -> hi/lo f16)
#pragma unroll
        for (int rr = 0; rr < 8; ++rr) {
            int v = tid + 256 * rr;
            int row = v >> 5, c4 = v & 31;
            unsigned h0, l0, h1, l1;
            cvt_hilo2(P[rr][0], P[rr][1], h0, l0);
            cvt_hilo2(P[rr][2], P[rr][3], h1, l1);
            int sidx = swz(row, c4 * 4);
            *reinterpret_cast<uint2*>(&sHi[sidx]) = make_uint2(h0, h1);
            *reinterpret_cast<uint2*>(&sLo[sidx]) = make_uint2(l0, l1);
        }
        __syncthreads();

        // ---- issue next tile's loads now; they fly under MFMA + epilogue
        const int tn = t + gridDim.x;
        const bool has_next = tn < ntiles;
        f32x4 Q[8]; int qi[4], qj[4];
        if (has_next) {
            const size_t base = (size_t)tn * 2048 + tid;
#pragma unroll
            for (int rr = 0; rr < 8; ++rr) Q[rr] = wv[base + 256 * rr];
#pragma unroll
            for (int mt = 0; mt < 4; ++mt) {
                int p = tn * 64 + mt * 16 + r;
                qi[mt] = idx_i[p]; qj[mt] = idx_j[p];
            }
        }

        // ---- MFMA: C'[n][m] += W1c^T(hi/lo) * wij^T(hi/lo), drop lo*lo
        f32x4 acc[2][4] = {};
#pragma unroll
        for (int ks = 0; ks < 4; ++ks) {
#pragma unroll
            for (int mt = 0; mt < 4; ++mt) {
                int ridx = swz(mt * 16 + r, ks * 32 + g * 8);
                half8 bh = *reinterpret_cast<const half8*>(&sHi[ridx]);
                half8 bl = *reinterpret_cast<const half8*>(&sLo[ridx]);
#pragma unroll
                for (int nt = 0; nt < 2; ++nt) {
                    acc[nt][mt] = MFMA16(Ahi[nt][ks], bh, acc[nt][mt]);
                    acc[nt][mt] = MFMA16(Alo[nt][ks], bh, acc[nt][mt]);
                    acc[nt][mt] = MFMA16(Ahi[nt][ks], bl, acc[nt][mt]);
                }
            }
        }

        // ---- epilogue: lane holds m = mt*16 + r (col), n = nt*16 + g*4 + e (row)
        const int m0 = t * 64;
#pragma unroll
        for (int mt = 0; mt < 4; ++mt) {
            int ni = pi[mt], nj = pj[mt];
            float ps = 0.f;
#pragma unroll
            for (int nt = 0; nt < 2; ++nt) {
                int nc = (wave * 2 + nt) * 16 + g * 4;
                f32x4 xa = *reinterpret_cast<const f32x4*>(&xab[(size_t)ni * 256 + nc]);
                f32x4 xb = *reinterpret_cast<const f32x4*>(&xab[(size_t)nj * 256 + 128 + nc]);
                f32x4 tv = acc[nt][mt] + b1v[nt] + xa + xb;
#pragma unroll
                for (int e = 0; e < 4; ++e) {
                    float te = tv[e];
                    float hh = te / (1.f + __expf(-te));   // silu
                    ps += hh * w2v[nt][e];
                }
            }
            ps += __shfl_xor(ps, 16);
            ps += __shfl_xor(ps, 32);
            if (g == 0) sred[wave][mt * 16 + r] = ps;
        }
        __syncthreads();
        if (wave == 0)
            out[m0 + lane] = b2v + sred[0][lane] + sred[1][lane] + sred[2][lane] + sred[3][lane];

        // ---- rotate prefetched registers into place
        if (has_next) {
#pragma unroll
            for (int rr = 0; rr < 8; ++rr) P[rr] = Q[rr];
#pragma unroll
            for (int mt = 0; mt < 4; ++mt) { pi[mt] = qi[mt]; pj[mt] = qj[mt]; }
        }
    }
}

extern "C" void kernel_launch(void* const* d_in, const int* in_sizes, int n_in,
                              void* d_out, int out_size, void* d_ws, size_t ws_size,
                              hipStream_t stream) {
    const float* x   = (const float*)d_in[0];
    const float* wij = (const float*)d_in[1];
    const float* W1  = (const float*)d_in[2];
    const float* b1  = (const float*)d_in[3];
    const float* W2  = (const float*)d_in[4];
    const float* b2  = (const float*)d_in[5];
    const int* ii    = (const int*)d_in[6];
    const int* jj    = (const int*)d_in[7];
    float* out = (float*)d_out;
    float* xab = (float*)d_ws;   // 50000*256*4 = 51.2 MB scratch

    dim3 gnode((NNODES + 63) / 64, 2);
    node_kernel<<<gnode, 256, 0, stream>>>(x, W1, xab);
    pair_kernel<<<768, 256, 0, stream>>>(wij, W1, b1, W2, b2, ii, jj, xab, out);
}